// Round 2
// baseline (208.913 us; speedup 1.0000x reference)
//
#include <hip/hip_runtime.h>

#define D   256
#define BM  64      // rows per block
#define BN  128     // codes per LDS chunk
#define KC  64      // k per LDS chunk (4 MFMA k-steps of 16); 4 chunks per full K

typedef __attribute__((ext_vector_type(8)))  short v8s;   // 8 bf16 = 4 VGPR
typedef __attribute__((ext_vector_type(4)))  float v4f;
typedef __attribute__((ext_vector_type(16))) float v16f;  // 32x32 accumulator
#define MFMA32 __builtin_amdgcn_mfma_f32_32x32x16_bf16

// counted vmcnt wait; "memory" clobber pins VMEM issue order around it so the
// per-wave outstanding-load accounting below is exact.
#define WAITVM(N) asm volatile("s_waitcnt vmcnt(" #N ")" ::: "memory")

static __device__ inline unsigned short f2bf(float f) {          // RNE
    unsigned u = __float_as_uint(f);
    return (unsigned short)((u + 0x7fffu + ((u >> 16) & 1u)) >> 16);
}
static __device__ inline float bf2f(unsigned short s) {
    return __uint_as_float(((unsigned)s) << 16);
}

// async global->LDS, 16 B per lane. LDS dest must be wave-uniform (HW adds lane*16).
static __device__ inline void gl_lds16(const unsigned short* g, unsigned short* l) {
    __builtin_amdgcn_global_load_lds(
        (const __attribute__((address_space(1))) unsigned int*)g,
        (__attribute__((address_space(3))) unsigned int*)l, 16, 0, 0);
}

// ---------------- kernel 1a: exact c2 ----------------
__global__ void vq_prep_c2(const float* __restrict__ cb, float* __restrict__ c2) {
    const int row  = blockIdx.x;
    const int lane = threadIdx.x;  // 64
    const float4 v = *reinterpret_cast<const float4*>(cb + (size_t)row * D + lane * 4);
    float s = v.x * v.x + v.y * v.y + v.z * v.z + v.w * v.w;
    #pragma unroll
    for (int off = 32; off > 0; off >>= 1) s += __shfl_down(s, off, 64);
    if (lane == 0) c2[row] = s;
}

// ---------------- kernel 1b: codebook -> bf16 hi/lo, chunk-major pre-swizzled ----------------
// Chunk (nc_i, kc_i) = 128 codes x 64 k = 1024 granules of 16 B (8 bf16).
// Granule p within chunk: seg = p>>7 (k-octet), q = p&127, code n = q ^ seg.
// Lane-linear DMA reproduces this in LDS: MFMA read octets (col 0..7, seg const)
// hit bank-groups (col^seg)&7, all distinct -> conflict-free.
__global__ void vq_prep_sw(const float* __restrict__ cb,
                           unsigned short* __restrict__ cbh, unsigned short* __restrict__ cbl) {
    const int chunk = blockIdx.x;          // 64 chunks
    const int nc = (chunk >> 2) * BN;
    const int kc = (chunk & 3) * KC;
    #pragma unroll
    for (int i = 0; i < 4; ++i) {
        const int p   = i * 256 + threadIdx.x;
        const int seg = p >> 7;
        const int n   = (p & 127) ^ seg;
        const float* src = cb + (size_t)(nc + n) * D + kc + seg * 8;
        const float4 f0 = *reinterpret_cast<const float4*>(src);
        const float4 f1 = *reinterpret_cast<const float4*>(src + 4);
        const float f[8] = {f0.x, f0.y, f0.z, f0.w, f1.x, f1.y, f1.z, f1.w};
        v8s h, l;
        #pragma unroll
        for (int j = 0; j < 8; ++j) {
            unsigned short hb = f2bf(f[j]);
            h[j] = (short)hb;
            l[j] = (short)f2bf(f[j] - bf2f(hb));
        }
        const size_t o = ((size_t)chunk * 1024 + p) * 8;
        *reinterpret_cast<v8s*>(cbh + o) = h;
        *reinterpret_cast<v8s*>(cbl + o) = l;
    }
}

// ---------------- kernel 2: 32x32 MFMA argmin + fused gather/loss ----------------
// Per chunk s (one unified compute region):
//   barrier1  : all waves done computing s-1 -> buffer par^1 reusable
//   issue s+1 : 8 global_load_lds into par^1 (flying through this chunk)
//   WAITVM(8) : own 8 stage-s loads landed (the 8 just-issued remain in flight)
//   barrier2  : every wave passed its WAITVM -> all of stage s is in LDS
//   compute   : 16 ds_read_b128 + 24 mfma_32x32x16 (setprio-wrapped)
// vmcnt never drains to 0 in the main loop. LDS read addrs precomputed in 8
// VGPRs; buffer parity / hi-lo selected by immediate offsets -> ~no loop VALU.
__global__ __launch_bounds__(256, 2) void vq_argmin_mfma(
        const float* __restrict__ x, const float* __restrict__ cb,
        const unsigned short* __restrict__ cbh, const unsigned short* __restrict__ cbl,
        const float* __restrict__ c2, float* __restrict__ idx_out,
        float* __restrict__ qout, float* __restrict__ partial, int N) {
    __shared__ unsigned short lds_h[2][BN * 8 * 8];   // 2 x 16 KB
    __shared__ unsigned short lds_l[2][BN * 8 * 8];   // 2 x 16 KB
    __shared__ float c2s[2048];                       // 8 KB  (total 72 KB -> 2 blocks/CU)

    const int tid  = threadIdx.x;
    const int w    = tid >> 6;
    const int lane = tid & 63;
    const int l31  = lane & 31;     // MFMA row (A) / col (B,C)
    const int hi   = lane >> 5;     // k-half selector
    const int mg   = w >> 1;        // 32-row half of the 64-row block tile
    const int ng   = w & 1;         // 64-col half of the 128-col group
    const int m0   = blockIdx.x * BM;
    const int n_groups = N >> 7;
    const int n_stages = n_groups * 4;

    // per-wave staging pointers: this wave stages granules [w*256, w*256+256)
    const unsigned short* gh0 = cbh + ((size_t)(w * 256 + lane)) * 8;
    const unsigned short* gl0 = cbl + ((size_t)(w * 256 + lane)) * 8;

    // issue stage-0 DMA first: it flies while we stage c2 and convert A below
    #pragma unroll
    for (int i = 0; i < 4; ++i) {
        gl_lds16(gh0 + i * 512, &lds_h[0][(w * 256 + i * 64) * 8]);
        gl_lds16(gl0 + i * 512, &lds_l[0][(w * 256 + i * 64) * 8]);
    }

    // ---- c2 -> LDS (read once per group later; removes global loads from loop) ----
    {
        const int o = tid * 8;
        if (o < N) {
            const float4 a = *reinterpret_cast<const float4*>(c2 + o);
            const float4 b = *reinterpret_cast<const float4*>(c2 + o + 4);
            *reinterpret_cast<float4*>(&c2s[o])     = a;
            *reinterpret_cast<float4*>(&c2s[o + 4]) = b;
        }
    }

    // ---- A-frags for 32x32x16: row = m0 + mg*32 + l31, k = ks*16 + hi*8 + j ----
    v8s xh[16], xl[16];
    {
        const float* xr = x + (size_t)(m0 + mg * 32 + l31) * D;
        #pragma unroll
        for (int ks = 0; ks < 16; ++ks) {
            const int kb = ks * 16 + hi * 8;
            const float4 f0 = *reinterpret_cast<const float4*>(xr + kb);
            const float4 f1 = *reinterpret_cast<const float4*>(xr + kb + 4);
            float f[8] = {f0.x, f0.y, f0.z, f0.w, f1.x, f1.y, f1.z, f1.w};
            v8s h, l;
            #pragma unroll
            for (int j = 0; j < 8; ++j) {
                unsigned short hb = f2bf(f[j]);
                h[j] = (short)hb;
                l[j] = (short)f2bf(f[j] - bf2f(hb));
            }
            xh[ks] = h; xl[ks] = l;
        }
    }

    // ---- precomputed swizzled LDS byte offsets (constant all kernel) ----
    // B-frag (ks,nt): lane reads chunk-code n = ng*64 + nt*32 + l31 at k-octet
    // seg = ks*2 + hi; stored granule p = seg*128 + (n ^ seg); byte off = p*16.
    unsigned aoff[4][2];
    #pragma unroll
    for (int ksl = 0; ksl < 4; ++ksl) {
        const int seg = ksl * 2 + hi;
        #pragma unroll
        for (int nt = 0; nt < 2; ++nt)
            aoff[ksl][nt] = (unsigned)((seg * 128 + ((ng * 64 + nt * 32 + l31) ^ seg)) * 16);
    }

    float runmin[16];
    int   runidx[16];
    #pragma unroll
    for (int r = 0; r < 16; ++r) { runmin[r] = 3.4e38f; runidx[r] = 0; }

    v16f acc[2];
    acc[0] = 0.0f; acc[1] = 0.0f;

    __syncthreads();   // publish c2s (prologue only; full drain acceptable here)

    for (int g = 0; g < n_groups; ++g) {
        #pragma unroll
        for (int cc = 0; cc < 4; ++cc) {           // compile-time chunk index
            const int par   = cc & 1;              // static buffer parity
            const int stage = g * 4 + cc;
            const bool more = (stage + 1 < n_stages);

            __builtin_amdgcn_s_barrier();          // barrier1: par^1 free for reuse
            if (more) {
                const unsigned short* gh = gh0 + (size_t)(stage + 1) * 8192;
                const unsigned short* gl = gl0 + (size_t)(stage + 1) * 8192;
                unsigned short* lh = lds_h[par ^ 1];
                unsigned short* ll = lds_l[par ^ 1];
                #pragma unroll
                for (int i = 0; i < 4; ++i) {
                    gl_lds16(gh + i * 512, lh + (w * 256 + i * 64) * 8);
                    gl_lds16(gl + i * 512, ll + (w * 256 + i * 64) * 8);
                }
                WAITVM(8);                         // own stage-s loads landed
            } else {
                WAITVM(0);                         // last stage: nothing younger
            }
            __builtin_amdgcn_s_barrier();          // barrier2: all waves' s in LDS

            __builtin_amdgcn_s_setprio(1);
            #pragma unroll
            for (int ksl = 0; ksl < 4; ++ksl) {
                const int ks = cc * 4 + ksl;       // static 0..15
                #pragma unroll
                for (int nt = 0; nt < 2; ++nt) {
                    const v8s ch = *reinterpret_cast<const v8s*>(
                        reinterpret_cast<const char*>(&lds_h[par][0]) + aoff[ksl][nt]);
                    const v8s cl = *reinterpret_cast<const v8s*>(
                        reinterpret_cast<const char*>(&lds_l[par][0]) + aoff[ksl][nt]);
                    acc[nt] = MFMA32(xh[ks], ch, acc[nt], 0, 0, 0);
                    acc[nt] = MFMA32(xl[ks], ch, acc[nt], 0, 0, 0);
                    acc[nt] = MFMA32(xh[ks], cl, acc[nt], 0, 0, 0);
                }
            }
            __builtin_amdgcn_s_setprio(0);
        }

        // finalize this n-group (registers + read-only c2s — no barrier needed)
        #pragma unroll
        for (int nt = 0; nt < 2; ++nt) {
            const int n = g * 128 + ng * 64 + nt * 32 + l31;
            const float c2n = c2s[n];
            #pragma unroll
            for (int r = 0; r < 16; ++r) {
                const float s = c2n - 2.0f * acc[nt][r];
                if (s < runmin[r]) { runmin[r] = s; runidx[r] = n; }
            }
            acc[nt] = 0.0f;
        }
    }

    // ---- merge: row = mg*32 + (r&3) + 8*(r>>2) + 4*hi ; slot = (ng*32+l31) ^ row ----
    __syncthreads();
    float* red_v = reinterpret_cast<float*>(&lds_h[0][0]);   // [64][64] f32, 16 KB
    int*   red_i = reinterpret_cast<int*>(&lds_h[1][0]);     // [64][64] i32, 16 KB
    #pragma unroll
    for (int r = 0; r < 16; ++r) {
        const int row  = mg * 32 + (r & 3) + 8 * (r >> 2) + 4 * hi;
        const int slot = (ng * 32 + l31) ^ row;              // bijective per row
        red_v[row * 64 + slot] = runmin[r];
        red_i[row * 64 + slot] = runidx[r];
    }
    __syncthreads();
    float best = 3.4e38f;
    int   bidx = 0;
    if (tid < 64) {
        #pragma unroll 4
        for (int t = 0; t < 64; ++t) {
            const int  sl = t ^ tid;                         // conflict-free scan
            const float v = red_v[tid * 64 + sl];
            const int  id = red_i[tid * 64 + sl];
            if (v < best || (v == best && id < bidx)) { best = v; bidx = id; }
        }
        idx_out[m0 + tid] = (float)bidx;
    }
    __syncthreads();
    int* idx_sh = reinterpret_cast<int*>(&lds_h[0][0]);
    if (tid < 64) idx_sh[tid] = bidx;
    __syncthreads();

    // ---- fused gather + loss over this block's 64 rows (x tile is L2-hot) ----
    const float* xg2 = x + (size_t)m0 * D;
    float s = 0.0f;
    #pragma unroll
    for (int i = 0; i < 16; ++i) {
        const int gix = i * 256 + tid;      // float4-granule, 4096 total
        const int row = gix >> 6;
        const int k4  = (gix & 63) * 4;
        const int idx = idx_sh[row];
        const float4 c  = *reinterpret_cast<const float4*>(cb  + (size_t)idx * D + k4);
        const float4 xv = *reinterpret_cast<const float4*>(xg2 + (size_t)row * D + k4);
        *reinterpret_cast<float4*>(qout + (size_t)(m0 + row) * D + k4) = c;
        const float dx = c.x - xv.x, dy = c.y - xv.y, dz = c.z - xv.z, dw = c.w - xv.w;
        s += dx * dx + dy * dy + dz * dz + dw * dw;
    }
    #pragma unroll
    for (int off = 32; off > 0; off >>= 1) s += __shfl_down(s, off, 64);
    float* wsum = reinterpret_cast<float*>(&lds_l[0][0]);
    if ((tid & 63) == 0) wsum[tid >> 6] = s;
    __syncthreads();
    if (tid == 0) partial[blockIdx.x] = wsum[0] + wsum[1] + wsum[2] + wsum[3];
}

// ---------------- kernel 3: final loss reduction ----------------
__global__ void vq_reduce_kernel(const float* __restrict__ partial, float* __restrict__ loss,
                                 float scale, int n) {
    __shared__ float red[4];
    const int tid = threadIdx.x;
    float s = 0.0f;
    for (int i = tid; i < n; i += 256) s += partial[i];
    #pragma unroll
    for (int off = 32; off > 0; off >>= 1) s += __shfl_down(s, off, 64);
    if ((tid & 63) == 0) red[tid >> 6] = s;
    __syncthreads();
    if (tid == 0) loss[0] = (red[0] + red[1] + red[2] + red[3]) * scale;
}

extern "C" void kernel_launch(void* const* d_in, const int* in_sizes, int n_in,
                              void* d_out, int out_size, void* d_ws, size_t ws_size,
                              hipStream_t stream) {
    const float* x  = (const float*)d_in[0];
    const float* cb = (const float*)d_in[1];
    const int M = in_sizes[0] / D;   // 32768
    const int N = in_sizes[1] / D;   // 2048

    float* qout    = (float*)d_out;
    float* idx_out = qout + (size_t)M * D;
    float* loss    = idx_out + M;

    // ws layout (bytes): c2 [0,8K) | cbh_sw [8K, +1M) | cbl_sw [+1M) | partial
    char* wsb = (char*)d_ws;
    float*          c2      = (float*)wsb;
    unsigned short* cbh     = (unsigned short*)(wsb + 8192);
    unsigned short* cbl     = cbh + (size_t)N * D;
    float*          partial = (float*)(wsb + 8192 + 2 * (size_t)N * D * sizeof(unsigned short));

    vq_prep_c2<<<N, 64, 0, stream>>>(cb, c2);
    vq_prep_sw<<<(N / BN) * (D / KC), 256, 0, stream>>>(cb, cbh, cbl);
    vq_argmin_mfma<<<M / BM, 256, 0, stream>>>(x, cb, cbh, cbl, c2, idx_out, qout, partial, N);
    const float scale = 2.0f / (float)((size_t)M * D);
    vq_reduce_kernel<<<1, 256, 0, stream>>>(partial, loss, scale, M / BM);
}